// Round 2
// baseline (171.638 us; speedup 1.0000x reference)
//
#include <hip/hip_runtime.h>

// RelationalGraphConvLayer: out[b,m,u] = relu(sum_e (adj[b,e]@feat[b]) @ ker[b,e])
// B=256, E=5, N=128, ATOM=64, UNITS=128, fp32 in/out, bf16 MFMA compute.
//
// v2 (resubmit; prior round was an infra failure, not a kernel verdict):
// 1024-thread blocks (16 waves/CU, 4/SIMD vs 2), adj+ker prefetched one e
// ahead into registers, and all LDS tiles stored in MFMA-fragment order so every
// hot-loop ds_read_b128 is addr = base + lane*16B (linear, conflict-free).

typedef __attribute__((ext_vector_type(8))) short s8v;  // 8 x bf16 (4 VGPRs) MFMA A/B frag
typedef __attribute__((ext_vector_type(4))) float f4v;  // MFMA C/D frag / float4 load

__device__ __forceinline__ short f2bf(float f) {
    // fp32 -> bf16 round-to-nearest-even (inputs finite; no NaN handling needed)
    unsigned u = __builtin_bit_cast(unsigned, f);
    u += 0x7FFFu + ((u >> 16) & 1u);
    return (short)(u >> 16);
}

__global__ __launch_bounds__(1024, 4)
void rgc_kernel(const float* __restrict__ adj,
                const float* __restrict__ feat,
                const float* __restrict__ ker,
                float* __restrict__ out)
{
    // Frag-order layouts: [tile][lane*8 shorts]. A wave's ds_read_b128 of one
    // tile is base + lane*16B -> linear 1KB, zero bank conflicts.
    __shared__ __align__(16) short featB[16 * 512];    // tile (d16*4+k16): feat[32k16+8q+j][16d16+c16] ; 16 KB
    __shared__ __align__(16) short kerB[2][16 * 512];  // tile (u16*2+k):   ker[32k+8q+j][16u16+c16]   ; 32 KB
    __shared__ __align__(16) short YA[16][2 * 512];    // per-wave, tile k: Y[16g+c16][32k+8q+j]       ; 32 KB

    const int tid  = threadIdx.x;
    const int w    = tid >> 6;    // wave 0..15
    const int lane = tid & 63;
    const int c16  = lane & 15;
    const int quad = lane >> 4;
    const int g    = w >> 1;      // row group: rows [16g, 16g+16)
    const int h    = w & 1;       // u-half: u16 tiles [4h, 4h+4)

    const int b = blockIdx.x;
    const float* adjB = adj  + (size_t)b * (5 * 128 * 128);
    const float* feG  = feat + (size_t)b * (128 * 64);
    const float* keG  = ker  + (size_t)b * (5 * 64 * 128);
    float*       outB = out  + (size_t)b * (128 * 128);

    // ---- adjacency e=0 into regs (consumed at loop top, reloaded for e+1) ----
    f4v a0[4], a1[4];
    {
        const float* ap = adjB + (16 * g + c16) * 128 + 8 * quad;
        #pragma unroll
        for (int k16 = 0; k16 < 4; ++k16) {
            a0[k16] = *(const f4v*)(ap + 32 * k16);
            a1[k16] = *(const f4v*)(ap + 32 * k16 + 4);
        }
    }

    // ---- stage featB once: column loads (lane = d -> coalesced), b128 write ----
    {
        const int fd  = tid & 63;        // d
        const int fn0 = (tid >> 6) * 8;  // n0 (8 consecutive n per thread)
        float fv[8];
        #pragma unroll
        for (int j = 0; j < 8; ++j)
            fv[j] = feG[(fn0 + j) * 64 + fd];
        s8v v;
        #pragma unroll
        for (int j = 0; j < 8; ++j) v[j] = f2bf(fv[j]);
        *(s8v*)&featB[((fd >> 4) * 4 + (fn0 >> 5)) * 512 + ((fn0 >> 3) & 3) * 128 + (fd & 15) * 8] = v;
    }

    // ---- stage kerB[0]: column loads (lane = u -> coalesced), b128 write ----
    const int ku  = tid & 127;        // u
    const int kd0 = (tid >> 7) * 8;   // d0 (8 consecutive d per thread)
    const int kerB_off = (ku >> 4) * 1024 + (kd0 >> 5) * 512 + ((kd0 >> 3) & 3) * 128 + (ku & 15) * 8;
    {
        float kv[8];
        #pragma unroll
        for (int j = 0; j < 8; ++j)
            kv[j] = keG[(kd0 + j) * 128 + ku];
        s8v v;
        #pragma unroll
        for (int j = 0; j < 8; ++j) v[j] = f2bf(kv[j]);
        *(s8v*)&kerB[0][kerB_off] = v;
    }
    __syncthreads();

    f4v oacc[4] = {};  // out tiles (m16 = g, u16 = 4h..4h+3)

    for (int e = 0; e < 5; ++e) {
        // ---- convert this e's adj regs to A-frags (frees a0/a1 for prefetch) ----
        s8v af[4];
        #pragma unroll
        for (int k16 = 0; k16 < 4; ++k16) {
            #pragma unroll
            for (int j = 0; j < 4; ++j) {
                af[k16][j]     = f2bf(a0[k16][j]);
                af[k16][4 + j] = f2bf(a1[k16][j]);
            }
        }

        // ---- prefetch e+1: ker columns then adj rows (waits land next iter) ----
        float kv[8];
        if (e < 4) {
            const float* kp = keG + (e + 1) * (64 * 128);
            #pragma unroll
            for (int j = 0; j < 8; ++j)
                kv[j] = kp[(kd0 + j) * 128 + ku];
            const float* ap = adjB + (e + 1) * (128 * 128) + (16 * g + c16) * 128 + 8 * quad;
            #pragma unroll
            for (int k16 = 0; k16 < 4; ++k16) {
                a0[k16] = *(const f4v*)(ap + 32 * k16);
                a1[k16] = *(const f4v*)(ap + 32 * k16 + 4);
            }
        }

        // ---- matmul1: Y[16g..16g+16) = adj_e @ feat (duplicated per wave pair) ----
        f4v yacc[4] = {};
        #pragma unroll
        for (int k16 = 0; k16 < 4; ++k16)
            #pragma unroll
            for (int d16 = 0; d16 < 4; ++d16) {
                s8v bf = *(const s8v*)&featB[(d16 * 4 + k16) * 512 + lane * 8];
                yacc[d16] = __builtin_amdgcn_mfma_f32_16x16x32_bf16(af[k16], bf, yacc[d16], 0, 0, 0);
            }

        // ---- Y -> wave-private LDS, stored directly in A-frag order ----
        // value yacc[d16][r] is Y[16g+4q+r][16d16+c16] -> tile k=d16>>1,
        // quad_t=(2d16+(c16>>3))&3, lane_c16=4q+r, j=c16&7.
        #pragma unroll
        for (int d16 = 0; d16 < 4; ++d16) {
            const int base = (d16 >> 1) * 512 + ((2 * d16 + (c16 >> 3)) & 3) * 128 + (c16 & 7);
            #pragma unroll
            for (int r = 0; r < 4; ++r)
                YA[w][base + (4 * quad + r) * 8] = f2bf(yacc[d16][r]);
        }

        // ---- matmul2: out[rows g][u-half h] += Y @ ker_e ----
        {
            const int buf = e & 1;
            s8v afr0 = *(const s8v*)&YA[w][lane * 8];
            s8v afr1 = *(const s8v*)&YA[w][512 + lane * 8];
            #pragma unroll
            for (int n = 0; n < 4; ++n) {
                const int u16 = 4 * h + n;
                s8v b0 = *(const s8v*)&kerB[buf][(u16 * 2 + 0) * 512 + lane * 8];
                s8v b1 = *(const s8v*)&kerB[buf][(u16 * 2 + 1) * 512 + lane * 8];
                oacc[n] = __builtin_amdgcn_mfma_f32_16x16x32_bf16(afr0, b0, oacc[n], 0, 0, 0);
                oacc[n] = __builtin_amdgcn_mfma_f32_16x16x32_bf16(afr1, b1, oacc[n], 0, 0, 0);
            }
        }

        // ---- stage next kerB into the other buffer; barrier protects rotation ----
        if (e < 4) {
            s8v v;
            #pragma unroll
            for (int j = 0; j < 8; ++j) v[j] = f2bf(kv[j]);
            *(s8v*)&kerB[(e + 1) & 1][kerB_off] = v;
            __syncthreads();
        }
    }

    // ---- epilogue: relu + store ----
    #pragma unroll
    for (int n = 0; n < 4; ++n)
        #pragma unroll
        for (int r = 0; r < 4; ++r)
            outB[(16 * g + 4 * quad + r) * 128 + 16 * (4 * h + n) + c16] = fmaxf(oacc[n][r], 0.f);
}

extern "C" void kernel_launch(void* const* d_in, const int* in_sizes, int n_in,
                              void* d_out, int out_size, void* d_ws, size_t ws_size,
                              hipStream_t stream)
{
    const float* adj  = (const float*)d_in[0];
    const float* feat = (const float*)d_in[1];
    const float* ker  = (const float*)d_in[2];
    rgc_kernel<<<256, 1024, 0, stream>>>(adj, feat, ker, (float*)d_out);
}

// Round 3
// 169.016 us; speedup vs baseline: 1.0155x; 1.0155x over previous
//
#include <hip/hip_runtime.h>

// RelationalGraphConvLayer: out[b,m,u] = relu(sum_e (adj[b,e]@feat[b]) @ ker[b,e])
// B=256, E=5, N=128, ATOM=64, UNITS=128, fp32 in/out, bf16 MFMA compute.
//
// v3 = v2 + real software pipeline:
//  - sched_barrier(0) pins the e+1 adj/ker prefetch loads at the top of the loop
//    (v2's VGPR_Count=52 proved the compiler sank them to their uses).
//  - per-iter __syncthreads() -> s_waitcnt lgkmcnt(0) + raw s_barrier, so the
//    prefetched global loads stay in flight across the barrier (the barrier only
//    protects the kerB LDS double-buffer rotation; vmcnt drain is unnecessary).

typedef __attribute__((ext_vector_type(8))) short s8v;  // 8 x bf16 (4 VGPRs) MFMA A/B frag
typedef __attribute__((ext_vector_type(4))) float f4v;  // MFMA C/D frag / float4 load

__device__ __forceinline__ short f2bf(float f) {
    // fp32 -> bf16 round-to-nearest-even (inputs finite; no NaN handling needed)
    unsigned u = __builtin_bit_cast(unsigned, f);
    u += 0x7FFFu + ((u >> 16) & 1u);
    return (short)(u >> 16);
}

// LDS-only barrier: drain this wave's LDS ops, then rendezvous. Global (vmcnt)
// loads stay outstanding across it. sched_barrier fences LDS-read hoisting.
__device__ __forceinline__ void lds_barrier() {
    asm volatile("s_waitcnt lgkmcnt(0)" ::: "memory");
    __builtin_amdgcn_s_barrier();
    __builtin_amdgcn_sched_barrier(0);
}

__global__ __launch_bounds__(1024, 4)
void rgc_kernel(const float* __restrict__ adj,
                const float* __restrict__ feat,
                const float* __restrict__ ker,
                float* __restrict__ out)
{
    // Frag-order layouts: [tile][lane*8 shorts]. A wave's ds_read_b128 of one
    // tile is base + lane*16B -> linear 1KB, zero bank conflicts.
    __shared__ __align__(16) short featB[16 * 512];    // tile (d16*4+k16): feat[32k16+8q+j][16d16+c16] ; 16 KB
    __shared__ __align__(16) short kerB[2][16 * 512];  // tile (u16*2+k):   ker[32k+8q+j][16u16+c16]   ; 32 KB
    __shared__ __align__(16) short YA[16][2 * 512];    // per-wave, tile k: Y[16g+c16][32k+8q+j]       ; 32 KB

    const int tid  = threadIdx.x;
    const int w    = tid >> 6;    // wave 0..15
    const int lane = tid & 63;
    const int c16  = lane & 15;
    const int quad = lane >> 4;
    const int g    = w >> 1;      // row group: rows [16g, 16g+16)
    const int h    = w & 1;       // u-half: u16 tiles [4h, 4h+4)

    const int b = blockIdx.x;
    const float* adjB = adj  + (size_t)b * (5 * 128 * 128);
    const float* feG  = feat + (size_t)b * (128 * 64);
    const float* keG  = ker  + (size_t)b * (5 * 64 * 128);
    float*       outB = out  + (size_t)b * (128 * 128);

    // ---- adjacency e=0 into regs (consumed at loop top, reloaded for e+1) ----
    f4v a0[4], a1[4];
    {
        const float* ap = adjB + (16 * g + c16) * 128 + 8 * quad;
        #pragma unroll
        for (int k16 = 0; k16 < 4; ++k16) {
            a0[k16] = *(const f4v*)(ap + 32 * k16);
            a1[k16] = *(const f4v*)(ap + 32 * k16 + 4);
        }
    }

    // ---- stage featB once: column loads (lane = d -> coalesced), b128 write ----
    {
        const int fd  = tid & 63;        // d
        const int fn0 = (tid >> 6) * 8;  // n0 (8 consecutive n per thread)
        float fv[8];
        #pragma unroll
        for (int j = 0; j < 8; ++j)
            fv[j] = feG[(fn0 + j) * 64 + fd];
        s8v v;
        #pragma unroll
        for (int j = 0; j < 8; ++j) v[j] = f2bf(fv[j]);
        *(s8v*)&featB[((fd >> 4) * 4 + (fn0 >> 5)) * 512 + ((fn0 >> 3) & 3) * 128 + (fd & 15) * 8] = v;
    }

    // ---- stage kerB[0]: column loads (lane = u -> coalesced), b128 write ----
    const int ku  = tid & 127;        // u
    const int kd0 = (tid >> 7) * 8;   // d0 (8 consecutive d per thread)
    const int kerB_off = (ku >> 4) * 1024 + (kd0 >> 5) * 512 + ((kd0 >> 3) & 3) * 128 + (ku & 15) * 8;
    {
        float kv[8];
        #pragma unroll
        for (int j = 0; j < 8; ++j)
            kv[j] = keG[(kd0 + j) * 128 + ku];
        s8v v;
        #pragma unroll
        for (int j = 0; j < 8; ++j) v[j] = f2bf(kv[j]);
        *(s8v*)&kerB[0][kerB_off] = v;
    }
    lds_barrier();

    f4v oacc[4] = {};  // out tiles (m16 = g, u16 = 4h..4h+3)

    for (int e = 0; e < 5; ++e) {
        // ---- convert this e's adj regs to A-frags (frees a0/a1 for prefetch) ----
        s8v af[4];
        #pragma unroll
        for (int k16 = 0; k16 < 4; ++k16) {
            #pragma unroll
            for (int j = 0; j < 4; ++j) {
                af[k16][j]     = f2bf(a0[k16][j]);
                af[k16][4 + j] = f2bf(a1[k16][j]);
            }
        }

        // ---- prefetch e+1: ker columns then adj rows; PINNED here so the
        //      latency is covered by matmul1+matmul2 below ----
        float kv[8];
        if (e < 4) {
            const float* kp = keG + (e + 1) * (64 * 128);
            #pragma unroll
            for (int j = 0; j < 8; ++j)
                kv[j] = kp[(kd0 + j) * 128 + ku];
            const float* ap = adjB + (e + 1) * (128 * 128) + (16 * g + c16) * 128 + 8 * quad;
            #pragma unroll
            for (int k16 = 0; k16 < 4; ++k16) {
                a0[k16] = *(const f4v*)(ap + 32 * k16);
                a1[k16] = *(const f4v*)(ap + 32 * k16 + 4);
            }
            __builtin_amdgcn_sched_barrier(0);  // loads may not sink below this point
        }

        // ---- matmul1: Y[16g..16g+16) = adj_e @ feat (duplicated per wave pair) ----
        f4v yacc[4] = {};
        #pragma unroll
        for (int k16 = 0; k16 < 4; ++k16)
            #pragma unroll
            for (int d16 = 0; d16 < 4; ++d16) {
                s8v bf = *(const s8v*)&featB[(d16 * 4 + k16) * 512 + lane * 8];
                yacc[d16] = __builtin_amdgcn_mfma_f32_16x16x32_bf16(af[k16], bf, yacc[d16], 0, 0, 0);
            }

        // ---- Y -> wave-private LDS, stored directly in A-frag order ----
        // value yacc[d16][r] is Y[16g+4q+r][16d16+c16] -> tile k=d16>>1,
        // quad_t=(2d16+(c16>>3))&3, lane_c16=4q+r, j=c16&7.
        #pragma unroll
        for (int d16 = 0; d16 < 4; ++d16) {
            const int base = (d16 >> 1) * 512 + ((2 * d16 + (c16 >> 3)) & 3) * 128 + (c16 & 7);
            #pragma unroll
            for (int r = 0; r < 4; ++r)
                YA[w][base + (4 * quad + r) * 8] = f2bf(yacc[d16][r]);
        }

        // ---- matmul2: out[rows g][u-half h] += Y @ ker_e ----
        {
            const int buf = e & 1;
            s8v afr0 = *(const s8v*)&YA[w][lane * 8];
            s8v afr1 = *(const s8v*)&YA[w][512 + lane * 8];
            #pragma unroll
            for (int n = 0; n < 4; ++n) {
                const int u16 = 4 * h + n;
                s8v b0 = *(const s8v*)&kerB[buf][(u16 * 2 + 0) * 512 + lane * 8];
                s8v b1 = *(const s8v*)&kerB[buf][(u16 * 2 + 1) * 512 + lane * 8];
                oacc[n] = __builtin_amdgcn_mfma_f32_16x16x32_bf16(afr0, b0, oacc[n], 0, 0, 0);
                oacc[n] = __builtin_amdgcn_mfma_f32_16x16x32_bf16(afr1, b1, oacc[n], 0, 0, 0);
            }
        }

        // ---- stage next kerB into the other buffer; LDS-only barrier protects
        //      the rotation (prefetched adj loads stay in flight) ----
        if (e < 4) {
            s8v v;
            #pragma unroll
            for (int j = 0; j < 8; ++j) v[j] = f2bf(kv[j]);
            *(s8v*)&kerB[(e + 1) & 1][kerB_off] = v;
            lds_barrier();
        }
    }

    // ---- epilogue: relu + store ----
    #pragma unroll
    for (int n = 0; n < 4; ++n)
        #pragma unroll
        for (int r = 0; r < 4; ++r)
            outB[(16 * g + 4 * quad + r) * 128 + 16 * (4 * h + n) + c16] = fmaxf(oacc[n][r], 0.f);
}

extern "C" void kernel_launch(void* const* d_in, const int* in_sizes, int n_in,
                              void* d_out, int out_size, void* d_ws, size_t ws_size,
                              hipStream_t stream)
{
    const float* adj  = (const float*)d_in[0];
    const float* feat = (const float*)d_in[1];
    const float* ker  = (const float*)d_in[2];
    rgc_kernel<<<256, 1024, 0, stream>>>(adj, feat, ker, (float*)d_out);
}